// Round 2
// baseline (723.156 us; speedup 1.0000x reference)
//
#include <hip/hip_runtime.h>
#include <math.h>

#define V 50000
#define E 300
#define H 2048
#define L 512
#define EH 2348  // E+H

// ---------------- kernel 1: attention scores = cat(emb_row, h0) @ attn_W.T + attn_b
__global__ void k_attn_scores(const int* __restrict__ token, const float* __restrict__ h0,
                              const float* __restrict__ emb, const float* __restrict__ attn_W,
                              const float* __restrict__ attn_b, float* __restrict__ scores) {
    int row = blockIdx.x;
    int tid = threadIdx.x;
    const float* erow = emb + (size_t)token[0] * E;
    const float* wrow = attn_W + (size_t)row * EH;
    float acc = 0.f;
    for (int j = tid; j < EH; j += 256) {
        float c = (j < E) ? erow[j] : h0[j - E];
        acc += c * wrow[j];
    }
    __shared__ float red[256];
    red[tid] = acc; __syncthreads();
    for (int s = 128; s > 0; s >>= 1) {
        if (tid < s) red[tid] += red[tid + s];
        __syncthreads();
    }
    if (tid == 0) scores[row] = red[0] + attn_b[row];
}

// ---------------- kernel 2: fused softmax + attn_apply partials
// grid = 32 blocks: lc = blockIdx.x>>3 (4 l-chunks of 128), hc = blockIdx.x&7 (8 h-chunks of 256)
// each block redundantly computes softmax over the 512 scores (cheap), then its partial
// apart[lc*H + h] = sum_{l in chunk} w[l] * enc[l][h].  Block 0 writes attn weights to d_out.
__global__ void k_attn_apply_sm(const float* __restrict__ scores, const float* __restrict__ enc,
                                float* __restrict__ apart, float* __restrict__ out_attnw) {
    __shared__ float sc[L];
    __shared__ float red[256];
    __shared__ float bcast;
    int tid = threadIdx.x;
    sc[tid] = scores[tid];
    sc[tid + 256] = scores[tid + 256];
    __syncthreads();
    // max
    red[tid] = fmaxf(sc[tid], sc[tid + 256]); __syncthreads();
    for (int s = 128; s > 0; s >>= 1) { if (tid < s) red[tid] = fmaxf(red[tid], red[tid + s]); __syncthreads(); }
    if (tid == 0) bcast = red[0];
    __syncthreads();
    float m = bcast;
    __syncthreads();
    sc[tid] = expf(sc[tid] - m);
    sc[tid + 256] = expf(sc[tid + 256] - m);
    __syncthreads();
    red[tid] = sc[tid] + sc[tid + 256]; __syncthreads();
    for (int s = 128; s > 0; s >>= 1) { if (tid < s) red[tid] += red[tid + s]; __syncthreads(); }
    if (tid == 0) bcast = red[0];
    __syncthreads();
    float inv_sum = 1.f / bcast;

    if (blockIdx.x == 0) {
        out_attnw[tid] = sc[tid] * inv_sum;
        out_attnw[tid + 256] = sc[tid + 256] * inv_sum;
    }
    int lc = blockIdx.x >> 3;
    int hc = blockIdx.x & 7;
    int h = hc * 256 + tid;
    float acc = 0.f;
    int l0 = lc * 128;
    for (int l = l0; l < l0 + 128; ++l) acc += sc[l] * enc[(size_t)l * H + h];
    apart[(size_t)lc * H + h] = acc * inv_sum;
}

// ---------------- kernel 3: x = relu(cat(emb_row, attn_applied) @ comb_W.T + comb_b)
// attn_applied[h] = sum of 4 partials
__global__ void k_combine(const int* __restrict__ token, const float* __restrict__ emb,
                          const float* __restrict__ apart, const float* __restrict__ comb_W,
                          const float* __restrict__ comb_b, float* __restrict__ x) {
    int row = blockIdx.x;
    int tid = threadIdx.x;
    const float* erow = emb + (size_t)token[0] * E;
    const float* wrow = comb_W + (size_t)row * EH;
    float acc = 0.f;
    for (int j = tid; j < EH; j += 256) {
        float c;
        if (j < E) c = erow[j];
        else {
            int h = j - E;
            c = apart[h] + apart[H + h] + apart[2 * H + h] + apart[3 * H + h];
        }
        acc += c * wrow[j];
    }
    __shared__ float red[256];
    red[tid] = acc; __syncthreads();
    for (int s = 128; s > 0; s >>= 1) {
        if (tid < s) red[tid] += red[tid + s];
        __syncthreads();
    }
    if (tid == 0) x[row] = fmaxf(red[0] + comb_b[row], 0.f);
}

// ---------------- kernel 4: fused GRU input+hidden GEMV, wave-per-row, float4
__global__ void k_gru_gemv(const float* __restrict__ x, const float* __restrict__ h0,
                           const float* __restrict__ W_ih, const float* __restrict__ W_hh,
                           const float* __restrict__ b_ih, const float* __restrict__ b_hh,
                           float* __restrict__ gi, float* __restrict__ gh) {
    int lane = threadIdx.x & 63;
    int wave = (blockIdx.x * blockDim.x + threadIdx.x) >> 6;
    int nw = (gridDim.x * blockDim.x) >> 6;
    const float4* x4 = (const float4*)x;
    const float4* h4 = (const float4*)h0;
    float4 xr[8], hr[8];
    #pragma unroll
    for (int i = 0; i < 8; i++) { xr[i] = x4[i * 64 + lane]; hr[i] = h4[i * 64 + lane]; }
    for (int r = wave; r < 2 * 3 * H; r += nw) {
        bool is_i = r < 3 * H;               // wave-uniform branch
        int row = is_i ? r : r - 3 * H;
        const float4* wrow = (const float4*)((is_i ? W_ih : W_hh) + (size_t)row * H);
        float acc0 = 0.f, acc1 = 0.f;
        #pragma unroll
        for (int i = 0; i < 8; i += 2) {
            float4 w0 = wrow[i * 64 + lane];
            float4 w1 = wrow[(i + 1) * 64 + lane];
            float4 v0 = is_i ? xr[i] : hr[i];
            float4 v1 = is_i ? xr[i + 1] : hr[i + 1];
            acc0 += v0.x * w0.x + v0.y * w0.y + v0.z * w0.z + v0.w * w0.w;
            acc1 += v1.x * w1.x + v1.y * w1.y + v1.z * w1.z + v1.w * w1.w;
        }
        float acc = acc0 + acc1;
        #pragma unroll
        for (int off = 32; off > 0; off >>= 1) acc += __shfl_xor(acc, off, 64);
        if (lane == 0) {
            if (is_i) gi[row] = acc + b_ih[row];
            else      gh[row] = acc + b_hh[row];
        }
    }
}

// ---------------- kernel 5: fused GRU-elementwise + output GEMV + online logsumexp partials
// Each block: recompute h_new into LDS (identical across blocks), then wave-per-row GEMV
// over out_W with online (m, s) tracking; block writes one (m,s) partial pair.
// Block 0 also writes h_new to d_out.
__global__ void k_out_gemv(const float* __restrict__ gi, const float* __restrict__ gh,
                           const float* __restrict__ h0, const float* __restrict__ out_W,
                           const float* __restrict__ out_b, float* __restrict__ logits,
                           float* __restrict__ pms, float* __restrict__ out_h) {
    __shared__ float4 hnew4[H / 4];
    float* hnew = (float*)hnew4;
    int tid = threadIdx.x;
    for (int j = tid; j < H; j += 256) {
        float r = 1.f / (1.f + expf(-(gi[j] + gh[j])));
        float z = 1.f / (1.f + expf(-(gi[H + j] + gh[H + j])));
        float n = tanhf(gi[2 * H + j] + r * gh[2 * H + j]);
        hnew[j] = (1.f - z) * n + z * h0[j];
    }
    __syncthreads();
    if (blockIdx.x == 0) {
        for (int j = tid; j < H; j += 256) out_h[j] = hnew[j];
    }
    int lane = tid & 63;
    int wib = tid >> 6;                       // wave in block (0..3)
    int wave = blockIdx.x * 4 + wib;
    int nw = gridDim.x * 4;
    float4 hreg[8];
    #pragma unroll
    for (int i = 0; i < 8; i++) hreg[i] = hnew4[i * 64 + lane];

    float m = -1e30f, s = 0.f;
    for (int r = wave; r < V; r += nw) {
        const float4* wrow = (const float4*)(out_W + (size_t)r * H);
        float acc0 = 0.f, acc1 = 0.f;
        #pragma unroll
        for (int i = 0; i < 8; i += 2) {
            float4 w0 = wrow[i * 64 + lane];
            float4 w1 = wrow[(i + 1) * 64 + lane];
            acc0 += hreg[i].x * w0.x + hreg[i].y * w0.y + hreg[i].z * w0.z + hreg[i].w * w0.w;
            acc1 += hreg[i + 1].x * w1.x + hreg[i + 1].y * w1.y + hreg[i + 1].z * w1.z + hreg[i + 1].w * w1.w;
        }
        float acc = acc0 + acc1;
        #pragma unroll
        for (int off = 32; off > 0; off >>= 1) acc += __shfl_xor(acc, off, 64);
        float xval = acc + out_b[r];           // all lanes hold the sum after butterfly
        if (lane == 0) logits[r] = xval;
        float mn = fmaxf(m, xval);
        s = s * expf(m - mn) + expf(xval - mn);
        m = mn;
    }
    // block reduce 4 wave-level (m,s) pairs
    __shared__ float ms[4], ss[4];
    if (lane == 0) { ms[wib] = m; ss[wib] = s; }
    __syncthreads();
    if (tid == 0) {
        float M = ms[0], S = ss[0];
        #pragma unroll
        for (int i = 1; i < 4; i++) {
            float Mn = fmaxf(M, ms[i]);
            S = S * expf(M - Mn) + ss[i] * expf(ms[i] - Mn);
            M = Mn;
        }
        pms[2 * blockIdx.x] = M;
        pms[2 * blockIdx.x + 1] = S;
    }
}

// ---------------- kernel 6: combine 2048 (m,s) partials -> C = logsumexp
__global__ void k_lse_final(const float* __restrict__ pms, float* __restrict__ C) {
    int tid = threadIdx.x;   // 1024 threads
    __shared__ float mred[1024], sred[1024];
    float m0 = pms[2 * tid], s0 = pms[2 * tid + 1];
    float m1 = pms[2 * (tid + 1024)], s1 = pms[2 * (tid + 1024) + 1];
    float M = fmaxf(m0, m1);
    float S = s0 * expf(m0 - M) + s1 * expf(m1 - M);
    mred[tid] = M; sred[tid] = S;
    __syncthreads();
    for (int s = 512; s > 0; s >>= 1) {
        if (tid < s) {
            float ma = mred[tid], mb = mred[tid + s];
            float Mn = fmaxf(ma, mb);
            sred[tid] = sred[tid] * expf(ma - Mn) + sred[tid + s] * expf(mb - Mn);
            mred[tid] = Mn;
        }
        __syncthreads();
    }
    if (tid == 0) C[0] = mred[0] + logf(sred[0]);
}

// ---------------- kernel 7: final log_softmax write
__global__ void k_logsoftmax(const float* __restrict__ logits, const float* __restrict__ C,
                             float* __restrict__ out) {
    int i = blockIdx.x * 256 + threadIdx.x;
    if (i < V) out[i] = logits[i] - C[0];
}

extern "C" void kernel_launch(void* const* d_in, const int* in_sizes, int n_in,
                              void* d_out, int out_size, void* d_ws, size_t ws_size,
                              hipStream_t stream) {
    const int*   token  = (const int*)d_in[0];
    const float* hidden = (const float*)d_in[1];   // [1,1,H]
    const float* enc    = (const float*)d_in[2];   // [L,H]
    const float* emb    = (const float*)d_in[3];   // [V,E]
    const float* attn_W = (const float*)d_in[4];   // [L,EH]
    const float* attn_b = (const float*)d_in[5];   // [L]
    const float* comb_W = (const float*)d_in[6];   // [H,EH]
    const float* comb_b = (const float*)d_in[7];   // [H]
    const float* W_ih   = (const float*)d_in[8];   // [3H,H]
    const float* W_hh   = (const float*)d_in[9];   // [3H,H]
    const float* b_ih   = (const float*)d_in[10];  // [3H]
    const float* b_hh   = (const float*)d_in[11];  // [3H]
    const float* out_W  = (const float*)d_in[12];  // [V,H]
    const float* out_b  = (const float*)d_in[13];  // [V]

    float* out = (float*)d_out;
    float* ws  = (float*)d_ws;

    // ws layout (floats), all offsets 16B-aligned
    float* scores = ws;              // 512
    float* apart  = ws + 512;        // 4*2048 = 8192
    float* xvec   = ws + 8704;       // 2048
    float* gi     = ws + 10752;      // 6144
    float* gh     = ws + 16896;      // 6144
    float* logits = ws + 23040;      // 50000
    float* pms    = ws + 73040;      // 2*2048 = 4096
    float* Cc     = ws + 77136;      // 1

    // d_out layout: output[50000] | h_new[2048] | attn_weights[512]
    float* out_logits = out;
    float* out_h      = out + V;
    float* out_attnw  = out + V + H;

    k_attn_scores<<<512, 256, 0, stream>>>(token, hidden, emb, attn_W, attn_b, scores);
    k_attn_apply_sm<<<32, 256, 0, stream>>>(scores, enc, apart, out_attnw);
    k_combine<<<2048, 256, 0, stream>>>(token, emb, apart, comb_W, comb_b, xvec);
    k_gru_gemv<<<1024, 256, 0, stream>>>(xvec, hidden, W_ih, W_hh, b_ih, b_hh, gi, gh);
    k_out_gemv<<<2048, 256, 0, stream>>>(gi, gh, hidden, out_W, out_b, logits, pms, out_h);
    k_lse_final<<<1, 1024, 0, stream>>>(pms, Cc);
    k_logsoftmax<<<196, 256, 0, stream>>>(logits, Cc, out_logits);
}